// Round 10
// baseline (60.165 us; speedup 1.0000x reference)
//
#include <hip/hip_runtime.h>

#define NQ   131072
#define PCNT 2048
#define NBIN 4096

typedef __attribute__((ext_vector_type(8))) short short8v;
typedef __attribute__((ext_vector_type(4))) float f32x4;

// ws layout (bytes)
#define HIST_OFF  0                           /* 16 KB */
#define H2_OFF    (NBIN * 4)                  /* 16 KB */
#define CTRL_OFF  (2 * NBIN * 4)              /* 32768, 256 B */
#define KEYS_OFF  (CTRL_OFF + 256)            /* NQ*4, 16B aligned */
#define CANDK_OFF (KEYS_OFF + NQ * 4)
#define CANDI_OFF (CANDK_OFF + NQ * 4)

// ctrl: [0]=B1 [1]=C1 [7]=cand count

__device__ __forceinline__ float sumsq_nc(float x, float y, float z) {
#pragma clang fp contract(off)
  return x * x + y * y + z * z;
}

__device__ __forceinline__ unsigned short bf_rne(float f) {
  unsigned u = __float_as_uint(f);
  return (unsigned short)((u + 0x7FFFu + ((u >> 16) & 1u)) >> 16);
}
__device__ __forceinline__ float bf2f(unsigned short h) {
  return __uint_as_float(((unsigned)h) << 16);
}
__device__ __forceinline__ unsigned fsort(float f) {
  unsigned u = __float_as_uint(f);
  return (u & 0x80000000u) ? ~u : (u | 0x80000000u);
}
__device__ __forceinline__ float funsort(unsigned u) {
  unsigned v = (u & 0x80000000u) ? (u ^ 0x80000000u) : ~u;
  return __uint_as_float(v);
}

// parallel "which thread's partial contains the need-th element" find
__device__ __forceinline__ void pfind256(unsigned mycnt, unsigned need,
                                         unsigned* wsum, unsigned* sel,
                                         unsigned* cum) {
  int t = threadIdx.x, lane = t & 63, wv = t >> 6;
  unsigned p = mycnt;
#pragma unroll
  for (int d = 1; d < 64; d <<= 1) {
    unsigned v = __shfl_up(p, d);
    if (lane >= d) p += v;
  }
  if (lane == 63) wsum[wv] = p;
  __syncthreads();
  unsigned base = 0;
  for (int w = 0; w < wv; ++w) base += wsum[w];
  unsigned pincl = p + base, pexcl = pincl - mycnt;
  if (pexcl < need && pincl >= need) { *sel = (unsigned)t; *cum = pexcl; }
  __syncthreads();
}

// 128 blocks x 256 x 4: keys + LDS 12-bit hist
__global__ __launch_bounds__(256) void k_keys(const float4* __restrict__ q4,
                                              uint4* __restrict__ keys4,
                                              unsigned* __restrict__ hist,
                                              unsigned* __restrict__ ctrl) {
  __shared__ unsigned h[NBIN];
  int t = threadIdx.x;
  for (int j = t; j < NBIN; j += 256) h[j] = 0;
  if (blockIdx.x == 0 && t < 8) ctrl[t] = 0;
  __syncthreads();
  int gid = blockIdx.x * 256 + t;
  int b = 3 * gid;
  float4 A = q4[b], B = q4[b + 1], C = q4[b + 2];
  float xs[4] = {A.x, A.w, B.z, C.y};
  float ys[4] = {A.y, B.x, B.w, C.z};
  float zs[4] = {A.z, B.y, C.x, C.w};
  unsigned kk[4];
#pragma unroll
  for (int l = 0; l < 4; ++l) {
    float s = sumsq_nc(xs[l], ys[l], zs[l]);
    float d = sqrtf(s) - 0.5f;
    kk[l] = __float_as_uint(fabsf(d));  // nonneg float: bits monotone
    atomicAdd(&h[kk[l] >> 20], 1u);
  }
  keys4[gid] = make_uint4(kk[0], kk[1], kk[2], kk[3]);
  __syncthreads();
  for (int j = t; j < NBIN; j += 256) {
    unsigned v = h[j];
    if (v) atomicAdd(&hist[j], v);
  }
}

// 128 blocks x 256 x 4: find B1; emit (key,idx) for top12<=B1; C1; h2 of B1
__global__ __launch_bounds__(256) void k_compact(const uint4* __restrict__ keys4,
                                                 const unsigned* __restrict__ hist,
                                                 unsigned* __restrict__ h2,
                                                 unsigned* __restrict__ ctrl,
                                                 unsigned* __restrict__ candk,
                                                 unsigned* __restrict__ candi) {
  __shared__ unsigned wsum[4];
  __shared__ unsigned sSel, sCum, sB1;
  __shared__ unsigned totC, totL, base, cur;
  int t = threadIdx.x;
  if (t == 0) { totC = 0; totL = 0; }
  const uint4* h4 = (const uint4*)hist;
  uint4 H0 = h4[4 * t], H1 = h4[4 * t + 1], H2v = h4[4 * t + 2], H3 = h4[4 * t + 3];
  unsigned r[16] = {H0.x, H0.y, H0.z, H0.w, H1.x, H1.y, H1.z, H1.w,
                    H2v.x, H2v.y, H2v.z, H2v.w, H3.x, H3.y, H3.z, H3.w};
  unsigned mycnt = 0;
#pragma unroll
  for (int j = 0; j < 16; ++j) mycnt += r[j];
  pfind256(mycnt, PCNT, wsum, &sSel, &sCum);
  if (t == (int)sSel) {
    unsigned cc = sCum; int found = -1;
#pragma unroll
    for (int j = 0; j < 16; ++j) {
      if (found < 0) { if (cc + r[j] >= PCNT) found = j; else cc += r[j]; }
    }
    sB1 = (unsigned)(t * 16 + found);
  }
  __syncthreads();
  unsigned B1 = sB1;
  if (blockIdx.x == 0 && t == 0) ctrl[0] = B1;
  int gid = blockIdx.x * 256 + t;
  uint4 kv = keys4[gid];
  unsigned ka[4] = {kv.x, kv.y, kv.z, kv.w};
  unsigned nM = 0, nL = 0;
#pragma unroll
  for (int l = 0; l < 4; ++l) {
    unsigned hb = ka[l] >> 20;
    nM += (hb <= B1); nL += (hb < B1);
  }
  if (nM) atomicAdd(&totC, nM);
  if (nL) atomicAdd(&totL, nL);
  __syncthreads();
  if (t == 0) {
    base = atomicAdd(&ctrl[7], totC);
    if (totL) atomicAdd(&ctrl[1], totL);
    cur = 0;
  }
  __syncthreads();
  int lane = t & 63;
#pragma unroll
  for (int l = 0; l < 4; ++l) {
    unsigned k = ka[l];
    bool m = (k >> 20) <= B1;
    unsigned long long mb = __ballot(m);
    unsigned wcnt = __popcll(mb);
    if (wcnt) {
      unsigned lb = 0;
      if (lane == 0) lb = atomicAdd(&cur, wcnt);
      lb = __shfl(lb, 0);
      if (m) {
        unsigned pos = base + lb + __popcll(mb & ((1ull << lane) - 1ull));
        candk[pos] = k;
        candi[pos] = (unsigned)(4 * gid + l);
        if ((k >> 20) == B1) atomicAdd(&h2[(k >> 8) & 0xFFFu], 1u);
      }
    }
  }
}

union frag_cast { uint4 u; short8v s; };

// 512 blocks x 256 (4 waves): per-block redundant exact select over cand
// (L2-resident) -> pack 2048 reps as bf16 hi/lo A-frags into LDS -> each
// wave holds a 512-rep chunk in regs (32 tiles x 4 VGPR) -> MFMA distance
// (hi/lo split, slots k0..13) -> LDS atomicMin combine -> fused epilogue.
__global__ __launch_bounds__(256) void k_mfma_sel(const float* __restrict__ q,
                                                  const unsigned* __restrict__ candk,
                                                  const unsigned* __restrict__ candi,
                                                  const unsigned* __restrict__ ctrl,
                                                  const unsigned* __restrict__ h2,
                                                  float* __restrict__ out) {
  __shared__ __align__(16) uint4 replp[PCNT];  // 32 KB packed frags
  __shared__ unsigned histC[256];
  __shared__ unsigned mnq[256];
  __shared__ unsigned wsum[4];
  __shared__ unsigned sSel, sCum, sB2, sCumB, sT, sCL, sK2, sCurL, sCurE;
  int t = threadIdx.x, lane = t & 63, w = t >> 6;
  int g = lane >> 4, ql = lane & 15;
  unsigned N = ctrl[7], B1 = ctrl[0], C1 = ctrl[1];
  unsigned needB = PCNT - C1;
  // P0: find B2 from global h2
  {
    const uint4* h24 = (const uint4*)h2;
    uint4 H0 = h24[4 * t], H1 = h24[4 * t + 1], H2v = h24[4 * t + 2], H3 = h24[4 * t + 3];
    unsigned r[16] = {H0.x, H0.y, H0.z, H0.w, H1.x, H1.y, H1.z, H1.w,
                      H2v.x, H2v.y, H2v.z, H2v.w, H3.x, H3.y, H3.z, H3.w};
    unsigned mycnt = 0;
#pragma unroll
    for (int j = 0; j < 16; ++j) mycnt += r[j];
    pfind256(mycnt, needB, wsum, &sSel, &sCum);
    if (t == (int)sSel) {
      unsigned cc = sCum; int found = -1;
#pragma unroll
      for (int j = 0; j < 16; ++j) {
        if (found < 0) { if (cc + r[j] >= needB) found = j; else cc += r[j]; }
      }
      sB2 = (unsigned)(t * 16 + found); sCumB = cc;
    }
  }
  histC[t] = 0;
  __syncthreads();
  unsigned B2 = sB2, cumB = sCumB, needC = needB - cumB;
  unsigned tgt = (B1 << 12) | B2;
  // P1: low-8 histogram of boundary-(B1,B2) candidates
  for (unsigned jb = 0; jb < N; jb += 256) {
    unsigned j = jb + t;
    if (j < N) {
      unsigned k = candk[j];
      if ((k >> 8) == tgt) atomicAdd(&histC[k & 0xFFu], 1u);
    }
  }
  __syncthreads();
  unsigned cbin = histC[t];
  pfind256(cbin, needC, wsum, &sSel, &sCum);
  if (t == (int)sSel) {
    unsigned CLv = C1 + cumB + sCum;
    sT = (B1 << 20) | (B2 << 8) | (unsigned)t;
    sCL = CLv; sK2 = PCNT - CLv;
  }
  if (t == 0) { sCurL = 0; sCurE = 0; }
  __syncthreads();
  unsigned T = sT, CL = sCL, K2 = sK2;
  // P2: gather selected reps, bf16 hi/lo pack, write frags to LDS
  for (unsigned jb = 0; jb < N; jb += 256) {
    unsigned j = jb + t;
    unsigned k = (j < N) ? candk[j] : 0xFFFFFFFFu;
    bool lt = k < T, eq = (k == T);
    unsigned long long ml = __ballot(lt), me = __ballot(eq);
    unsigned wl = __popcll(ml), we = __popcll(me);
    unsigned bl = 0, be = 0;
    if (wl) { if (lane == 0) bl = atomicAdd(&sCurL, wl); bl = __shfl(bl, 0); }
    if (we) { if (lane == 0) be = atomicAdd(&sCurE, we); be = __shfl(be, 0); }
    int pos = -1;
    if (lt) pos = (int)(bl + __popcll(ml & ((1ull << lane) - 1ull)));
    else if (eq) {
      unsigned e = be + __popcll(me & ((1ull << lane) - 1ull));
      if (e < K2) pos = (int)(CL + e);
    }
    if (pos >= 0) {
      unsigned i = candi[j];
      float x = q[3 * i], y = q[3 * i + 1], z = q[3 * i + 2];
      float r2 = sumsq_nc(x, y, z);
      unsigned short r2h = bf_rne(r2);
      unsigned short r2l = bf_rne(r2 - bf2f(r2h));
      float cx = -2.0f * x, cy = -2.0f * y, cz = -2.0f * z;
      unsigned short hx = bf_rne(cx), hy = bf_rne(cy), hz = bf_rne(cz);
      unsigned short lx = bf_rne(cx - bf2f(hx));
      unsigned short ly = bf_rne(cy - bf2f(hy));
      unsigned short lz = bf_rne(cz - bf2f(hz));
      replp[pos] = make_uint4((unsigned)r2h | ((unsigned)r2l << 16),
                              (unsigned)hx | ((unsigned)hy << 16),
                              (unsigned)hz | ((unsigned)lx << 16),
                              (unsigned)ly | ((unsigned)lz << 16));
    }
  }
  mnq[t] = 0xFFFFFFFFu;
  __syncthreads();
  // Phase D: wave w's 512-rep chunk -> regs (g==1 gets dword-shifted frag
  // for k8-15 slots; g2,g3 multiply zero B so content moot)
  uint4 raw[32];
#pragma unroll
  for (int j = 0; j < 32; ++j) raw[j] = replp[w * 512 + j * 16 + ql];
  bool gs = (g == 1);
#pragma unroll
  for (int j = 0; j < 32; ++j) {
    uint4 v = raw[j];
    raw[j] = gs ? make_uint4(v.y, v.z, v.w, 0u) : v;
  }
  int qbase = blockIdx.x * 256;
  const unsigned one2 = 0x3F803F80u;  // (1.0bf16, 1.0bf16)
  f32x4 zero4 = {0.f, 0.f, 0.f, 0.f};
  for (int qt = 0; qt < 16; ++qt) {
    int qi = qbase + qt * 16 + ql;
    float x = q[3 * qi], y = q[3 * qi + 1], z = q[3 * qi + 2];
    unsigned short hx = bf_rne(x), hy = bf_rne(y), hz = bf_rne(z);
    unsigned short lx = bf_rne(x - bf2f(hx));
    unsigned short ly = bf_rne(y - bf2f(hy));
    unsigned short lz = bf_rne(z - bf2f(hz));
    // B slots k0-7 (g0): [1,1,qh0,qh1,qh2,qh0,qh1,qh2]
    // B slots k8-15 (g1): [ql0,ql1,ql2,ql0,ql1,ql2,0,0]; g2,g3: zeros
    uint4 bu;
    if (g == 0) {
      bu = make_uint4(one2,
                      (unsigned)hx | ((unsigned)hy << 16),
                      (unsigned)hz | ((unsigned)hx << 16),
                      (unsigned)hy | ((unsigned)hz << 16));
    } else if (g == 1) {
      bu = make_uint4((unsigned)lx | ((unsigned)ly << 16),
                      (unsigned)lz | ((unsigned)lx << 16),
                      (unsigned)ly | ((unsigned)lz << 16), 0u);
    } else {
      bu = make_uint4(0u, 0u, 0u, 0u);
    }
    frag_cast bf; bf.u = bu;
    float mn = 1e30f;
#pragma unroll
    for (int j = 0; j < 32; ++j) {
      frag_cast af; af.u = raw[j];
      f32x4 d = __builtin_amdgcn_mfma_f32_16x16x32_bf16(af.s, bf.s, zero4, 0, 0, 0);
      mn = fminf(mn, fminf(fminf(d[0], d[1]), fminf(d[2], d[3])));
    }
    mn = fminf(mn, __shfl_xor(mn, 16));
    mn = fminf(mn, __shfl_xor(mn, 32));
    if (g == 0) atomicMin(&mnq[qt * 16 + ql], fsort(mn));
  }
  __syncthreads();
  // epilogue: thread t <-> query qbase + t
  int i = qbase + t;
  float tmin = funsort(mnq[t]);
  float x = q[3 * i], y = q[3 * i + 1], z = q[3 * i + 2];
  float s = sumsq_nc(x, y, z);
  float d = sqrtf(s) - 0.5f;
  float d2 = fmaxf(s + tmin, 0.0f);
  float nd = (d2 > 0.0f) ? sqrtf(d2) : 0.0f;
  float sg = (d > 0.0f) ? 1.0f : ((d < 0.0f) ? -1.0f : 0.0f);
  out[i] = fminf(nd * sg, d);
}

extern "C" void kernel_launch(void* const* d_in, const int* in_sizes, int n_in,
                              void* d_out, int out_size, void* d_ws, size_t ws_size,
                              hipStream_t stream) {
  const float* q = (const float*)d_in[0];
  float* out = (float*)d_out;
  char* ws = (char*)d_ws;

  unsigned* hist  = (unsigned*)(ws + HIST_OFF);
  unsigned* h2    = (unsigned*)(ws + H2_OFF);
  unsigned* ctrl  = (unsigned*)(ws + CTRL_OFF);
  uint4*    keys4 = (uint4*)(ws + KEYS_OFF);
  unsigned* candk = (unsigned*)(ws + CANDK_OFF);
  unsigned* candi = (unsigned*)(ws + CANDI_OFF);

  hipMemsetAsync(hist, 0, 2 * NBIN * 4, stream);
  k_keys<<<128, 256, 0, stream>>>((const float4*)q, keys4, hist, ctrl);
  k_compact<<<128, 256, 0, stream>>>(keys4, hist, h2, ctrl, candk, candi);
  k_mfma_sel<<<NQ / 256, 256, 0, stream>>>(q, candk, candi, ctrl, h2, out);
}

// Round 11
// 42.074 us; speedup vs baseline: 1.4300x; 1.4300x over previous
//
#include <hip/hip_runtime.h>

#define NQ   131072
#define PCNT 2048
#define NBIN 4096

typedef __attribute__((ext_vector_type(8))) short short8v;
typedef __attribute__((ext_vector_type(16))) float f32x16;

// ws layout (bytes)
#define HIST_OFF  0                           /* 16 KB */
#define H2_OFF    (NBIN * 4)                  /* 16 KB */
#define CTRL_OFF  (2 * NBIN * 4)              /* 32768, 256 B */
#define KEYS_OFF  (CTRL_OFF + 256)            /* NQ*4, 16B aligned */
#define CANDK_OFF (KEYS_OFF + NQ * 4)
#define CANDI_OFF (CANDK_OFF + NQ * 4)
#define REPP_OFF  (CANDI_OFF + NQ * 4)        /* PCNT*16 packed frags */

// ctrl: [0]=B1 [1]=C1 [5]=curL [6]=curE [7]=cand count

__device__ __forceinline__ float sumsq_nc(float x, float y, float z) {
#pragma clang fp contract(off)
  return x * x + y * y + z * z;
}

__device__ __forceinline__ unsigned short bf_rne(float f) {
  unsigned u = __float_as_uint(f);
  return (unsigned short)((u + 0x7FFFu + ((u >> 16) & 1u)) >> 16);
}
__device__ __forceinline__ float bf2f(unsigned short h) {
  return __uint_as_float(((unsigned)h) << 16);
}
__device__ __forceinline__ unsigned fsort(float f) {
  unsigned u = __float_as_uint(f);
  return (u & 0x80000000u) ? ~u : (u | 0x80000000u);
}
__device__ __forceinline__ float funsort(unsigned u) {
  unsigned v = (u & 0x80000000u) ? (u ^ 0x80000000u) : ~u;
  return __uint_as_float(v);
}

// parallel "which thread's partial contains the need-th element" find
__device__ __forceinline__ void pfind256(unsigned mycnt, unsigned need,
                                         unsigned* wsum, unsigned* sel,
                                         unsigned* cum) {
  int t = threadIdx.x, lane = t & 63, wv = t >> 6;
  unsigned p = mycnt;
#pragma unroll
  for (int d = 1; d < 64; d <<= 1) {
    unsigned v = __shfl_up(p, d);
    if (lane >= d) p += v;
  }
  if (lane == 63) wsum[wv] = p;
  __syncthreads();
  unsigned base = 0;
  for (int w = 0; w < wv; ++w) base += wsum[w];
  unsigned pincl = p + base, pexcl = pincl - mycnt;
  if (pexcl < need && pincl >= need) { *sel = (unsigned)t; *cum = pexcl; }
  __syncthreads();
}

// 128 blocks x 256 x 4: keys + LDS 12-bit hist
__global__ __launch_bounds__(256) void k_keys(const float4* __restrict__ q4,
                                              uint4* __restrict__ keys4,
                                              unsigned* __restrict__ hist,
                                              unsigned* __restrict__ ctrl) {
  __shared__ unsigned h[NBIN];
  int t = threadIdx.x;
  for (int j = t; j < NBIN; j += 256) h[j] = 0;
  if (blockIdx.x == 0 && t < 8) ctrl[t] = 0;
  __syncthreads();
  int gid = blockIdx.x * 256 + t;
  int b = 3 * gid;
  float4 A = q4[b], B = q4[b + 1], C = q4[b + 2];
  float xs[4] = {A.x, A.w, B.z, C.y};
  float ys[4] = {A.y, B.x, B.w, C.z};
  float zs[4] = {A.z, B.y, C.x, C.w};
  unsigned kk[4];
#pragma unroll
  for (int l = 0; l < 4; ++l) {
    float s = sumsq_nc(xs[l], ys[l], zs[l]);
    float d = sqrtf(s) - 0.5f;
    kk[l] = __float_as_uint(fabsf(d));  // nonneg float: bits monotone
    atomicAdd(&h[kk[l] >> 20], 1u);
  }
  keys4[gid] = make_uint4(kk[0], kk[1], kk[2], kk[3]);
  __syncthreads();
  for (int j = t; j < NBIN; j += 256) {
    unsigned v = h[j];
    if (v) atomicAdd(&hist[j], v);
  }
}

// 128 blocks x 256 x 4: find B1; emit (key,idx) for top12<=B1; C1; h2 of B1
__global__ __launch_bounds__(256) void k_compact(const uint4* __restrict__ keys4,
                                                 const unsigned* __restrict__ hist,
                                                 unsigned* __restrict__ h2,
                                                 unsigned* __restrict__ ctrl,
                                                 unsigned* __restrict__ candk,
                                                 unsigned* __restrict__ candi) {
  __shared__ unsigned wsum[4];
  __shared__ unsigned sSel, sCum, sB1;
  __shared__ unsigned totC, totL, base, cur;
  int t = threadIdx.x;
  if (t == 0) { totC = 0; totL = 0; }
  const uint4* h4 = (const uint4*)hist;
  uint4 H0 = h4[4 * t], H1 = h4[4 * t + 1], H2v = h4[4 * t + 2], H3 = h4[4 * t + 3];
  unsigned r[16] = {H0.x, H0.y, H0.z, H0.w, H1.x, H1.y, H1.z, H1.w,
                    H2v.x, H2v.y, H2v.z, H2v.w, H3.x, H3.y, H3.z, H3.w};
  unsigned mycnt = 0;
#pragma unroll
  for (int j = 0; j < 16; ++j) mycnt += r[j];
  pfind256(mycnt, PCNT, wsum, &sSel, &sCum);
  if (t == (int)sSel) {
    unsigned cc = sCum; int found = -1;
#pragma unroll
    for (int j = 0; j < 16; ++j) {
      if (found < 0) { if (cc + r[j] >= PCNT) found = j; else cc += r[j]; }
    }
    sB1 = (unsigned)(t * 16 + found);
  }
  __syncthreads();
  unsigned B1 = sB1;
  if (blockIdx.x == 0 && t == 0) ctrl[0] = B1;
  int gid = blockIdx.x * 256 + t;
  uint4 kv = keys4[gid];
  unsigned ka[4] = {kv.x, kv.y, kv.z, kv.w};
  unsigned nM = 0, nL = 0;
#pragma unroll
  for (int l = 0; l < 4; ++l) {
    unsigned hb = ka[l] >> 20;
    nM += (hb <= B1); nL += (hb < B1);
  }
  if (nM) atomicAdd(&totC, nM);
  if (nL) atomicAdd(&totL, nL);
  __syncthreads();
  if (t == 0) {
    base = atomicAdd(&ctrl[7], totC);
    if (totL) atomicAdd(&ctrl[1], totL);
    cur = 0;
  }
  __syncthreads();
  int lane = t & 63;
#pragma unroll
  for (int l = 0; l < 4; ++l) {
    unsigned k = ka[l];
    bool m = (k >> 20) <= B1;
    unsigned long long mb = __ballot(m);
    unsigned wcnt = __popcll(mb);
    if (wcnt) {
      unsigned lb = 0;
      if (lane == 0) lb = atomicAdd(&cur, wcnt);
      lb = __shfl(lb, 0);
      if (m) {
        unsigned pos = base + lb + __popcll(mb & ((1ull << lane) - 1ull));
        candk[pos] = k;
        candi[pos] = (unsigned)(4 * gid + l);
        if ((k >> 20) == B1) atomicAdd(&h2[(k >> 8) & 0xFFFu], 1u);
      }
    }
  }
}

// 32 blocks x 256: exact select (redundant per block) + pack selected reps as
// MFMA A-fragments: [r2h, r2l, -2rh0..2, -2rl0..2] as 8 bf16 in one uint4
__global__ __launch_bounds__(256) void k_prep(const float* __restrict__ q,
                                              const unsigned* __restrict__ candk,
                                              const unsigned* __restrict__ candi,
                                              unsigned* __restrict__ ctrl,
                                              const unsigned* __restrict__ h2,
                                              uint4* __restrict__ repp) {
  __shared__ unsigned histC[256];
  __shared__ unsigned wsum[4];
  __shared__ unsigned sSel, sCum, sB2, sCumB, sT, sCL, sK2;
  int t = threadIdx.x, lane = t & 63;
  unsigned N = ctrl[7], B1 = ctrl[0], C1 = ctrl[1];
  unsigned needB = PCNT - C1;
  {
    const uint4* h24 = (const uint4*)h2;
    uint4 H0 = h24[4 * t], H1 = h24[4 * t + 1], H2v = h24[4 * t + 2], H3 = h24[4 * t + 3];
    unsigned r[16] = {H0.x, H0.y, H0.z, H0.w, H1.x, H1.y, H1.z, H1.w,
                      H2v.x, H2v.y, H2v.z, H2v.w, H3.x, H3.y, H3.z, H3.w};
    unsigned mycnt = 0;
#pragma unroll
    for (int j = 0; j < 16; ++j) mycnt += r[j];
    pfind256(mycnt, needB, wsum, &sSel, &sCum);
    if (t == (int)sSel) {
      unsigned cc = sCum; int found = -1;
#pragma unroll
      for (int j = 0; j < 16; ++j) {
        if (found < 0) { if (cc + r[j] >= needB) found = j; else cc += r[j]; }
      }
      sB2 = (unsigned)(t * 16 + found); sCumB = cc;
    }
  }
  histC[t] = 0;
  __syncthreads();
  unsigned B2 = sB2, cumB = sCumB, needC = needB - cumB;
  unsigned tgt = (B1 << 12) | B2;
  for (unsigned jb = 0; jb < N; jb += 256) {
    unsigned j = jb + t;
    if (j < N) {
      unsigned k = candk[j];
      if ((k >> 8) == tgt) atomicAdd(&histC[k & 0xFFu], 1u);
    }
  }
  __syncthreads();
  unsigned cbin = histC[t];
  pfind256(cbin, needC, wsum, &sSel, &sCum);
  if (t == (int)sSel) {
    unsigned CLv = C1 + cumB + sCum;
    sT = (B1 << 20) | (B2 << 8) | (unsigned)t;
    sCL = CLv; sK2 = PCNT - CLv;
  }
  __syncthreads();
  unsigned T = sT, CL = sCL, K2 = sK2;
  // slice of cand per block; global cursors for positions
  unsigned S = (N + 31) / 32;
  unsigned jlo = blockIdx.x * S, jhi = min(N, jlo + S);
  for (unsigned jb = jlo; jb < jhi; jb += 256) {
    unsigned j = jb + t;
    unsigned k = (j < jhi) ? candk[j] : 0xFFFFFFFFu;
    bool lt = k < T, eq = (k == T);
    unsigned long long ml = __ballot(lt), me = __ballot(eq);
    unsigned wl = __popcll(ml), we = __popcll(me);
    unsigned bl = 0, be = 0;
    if (wl) { if (lane == 0) bl = atomicAdd(&ctrl[5], wl); bl = __shfl(bl, 0); }
    if (we) { if (lane == 0) be = atomicAdd(&ctrl[6], we); be = __shfl(be, 0); }
    int pos = -1;
    if (lt) pos = (int)(bl + __popcll(ml & ((1ull << lane) - 1ull)));
    else if (eq) {
      unsigned e = be + __popcll(me & ((1ull << lane) - 1ull));
      if (e < K2) pos = (int)(CL + e);
    }
    if (pos >= 0) {
      unsigned i = candi[j];
      float x = q[3 * i], y = q[3 * i + 1], z = q[3 * i + 2];
      float r2 = sumsq_nc(x, y, z);
      unsigned short r2h = bf_rne(r2);
      unsigned short r2l = bf_rne(r2 - bf2f(r2h));
      float cx = -2.0f * x, cy = -2.0f * y, cz = -2.0f * z;
      unsigned short hx = bf_rne(cx), hy = bf_rne(cy), hz = bf_rne(cz);
      unsigned short lx = bf_rne(cx - bf2f(hx));
      unsigned short ly = bf_rne(cy - bf2f(hy));
      unsigned short lz = bf_rne(cz - bf2f(hz));
      repp[pos] = make_uint4((unsigned)r2h | ((unsigned)r2l << 16),
                             (unsigned)hx | ((unsigned)hy << 16),
                             (unsigned)hz | ((unsigned)lx << 16),
                             (unsigned)ly | ((unsigned)lz << 16));
    }
  }
}

union frag_cast { uint4 u; short8v s; };

// 512 blocks x 256 (4 waves): 32x32x16 MFMA. Each wave holds a 512-rep chunk
// as 16 A-tiles (64 VGPR); B-frags packed ONCE per query into LDS at stage.
// A lanes 0-31: k0-7 = [r2h,r2l,H,L]; lanes 32-63: k8-15 = dword-shifted.
// D: col=lane&31, rows split across lane halves -> min over 16 regs +
// shfl_xor(32) + LDS atomicMin. Fused epilogue (q^2 cached in LDS).
__global__ __launch_bounds__(256) void k_mfma(const float* __restrict__ q,
                                              const uint4* __restrict__ repp,
                                              float* __restrict__ out) {
  __shared__ __align__(16) uint4 b0l[256];  // 4 KB B-frag k0-7 per query
  __shared__ __align__(16) uint4 b1l[256];  // 4 KB B-frag k8-15 per query
  __shared__ float ssl[256];
  __shared__ unsigned mnq[256];
  int t = threadIdx.x, lane = t & 63, w = t >> 6;
  int g = lane >> 5, col = lane & 31;
  int qbase = blockIdx.x * 256;
  // stage: each thread packs its own query (hi/lo bf16) + caches q^2
  {
    int i = qbase + t;
    float x = q[3 * i], y = q[3 * i + 1], z = q[3 * i + 2];
    float s = sumsq_nc(x, y, z);
    ssl[t] = s;
    mnq[t] = 0xFFFFFFFFu;
    unsigned short hx = bf_rne(x), hy = bf_rne(y), hz = bf_rne(z);
    unsigned short lx = bf_rne(x - bf2f(hx));
    unsigned short ly = bf_rne(y - bf2f(hy));
    unsigned short lz = bf_rne(z - bf2f(hz));
    b0l[t] = make_uint4(0x3F803F80u,  // (1.0, 1.0) bf16 -> r2h, r2l slots
                        (unsigned)hx | ((unsigned)hy << 16),
                        (unsigned)hz | ((unsigned)hx << 16),
                        (unsigned)hy | ((unsigned)hz << 16));
    b1l[t] = make_uint4((unsigned)lx | ((unsigned)ly << 16),
                        (unsigned)lz | ((unsigned)lx << 16),
                        (unsigned)ly | ((unsigned)lz << 16), 0u);
  }
  // load this wave's 16 A-tiles (512 reps); g==1 lanes use dword-shifted
  // frags (k8-15 slots)
  uint4 raw[16];
  const uint4* rp = repp + w * 512;
#pragma unroll
  for (int j = 0; j < 16; ++j) raw[j] = rp[j * 32 + col];
  bool gs = (g == 1);
#pragma unroll
  for (int j = 0; j < 16; ++j) {
    uint4 v = raw[j];
    raw[j] = gs ? make_uint4(v.y, v.z, v.w, 0u) : v;
  }
  __syncthreads();
  const uint4* bp = gs ? b1l : b0l;
  f32x16 zero16 = {0.f, 0.f, 0.f, 0.f, 0.f, 0.f, 0.f, 0.f,
                   0.f, 0.f, 0.f, 0.f, 0.f, 0.f, 0.f, 0.f};
  for (int qt = 0; qt < 8; ++qt) {
    frag_cast bf; bf.u = bp[qt * 32 + col];
    float mn = 1e30f;
#pragma unroll
    for (int j = 0; j < 16; ++j) {
      frag_cast af; af.u = raw[j];
      f32x16 d = __builtin_amdgcn_mfma_f32_32x32x16_bf16(af.s, bf.s, zero16, 0, 0, 0);
      float m = fminf(fminf(d[0], d[1]), d[2]);      // v_min3 chains
      m = fminf(fminf(m, d[3]), d[4]);
      m = fminf(fminf(m, d[5]), d[6]);
      m = fminf(fminf(m, d[7]), d[8]);
      m = fminf(fminf(m, d[9]), d[10]);
      m = fminf(fminf(m, d[11]), d[12]);
      m = fminf(fminf(m, d[13]), d[14]);
      mn = fminf(fminf(mn, m), d[15]);
    }
    mn = fminf(mn, __shfl_xor(mn, 32));  // combine row-halves (lane pairs)
    if (g == 0) atomicMin(&mnq[qt * 32 + col], fsort(mn));
  }
  __syncthreads();
  // epilogue: thread t <-> query qbase + t
  int i = qbase + t;
  float tmin = funsort(mnq[t]);
  float s = ssl[t];
  float d = sqrtf(s) - 0.5f;
  float d2 = fmaxf(s + tmin, 0.0f);
  float nd = (d2 > 0.0f) ? sqrtf(d2) : 0.0f;
  float sg = (d > 0.0f) ? 1.0f : ((d < 0.0f) ? -1.0f : 0.0f);
  out[i] = fminf(nd * sg, d);
}

extern "C" void kernel_launch(void* const* d_in, const int* in_sizes, int n_in,
                              void* d_out, int out_size, void* d_ws, size_t ws_size,
                              hipStream_t stream) {
  const float* q = (const float*)d_in[0];
  float* out = (float*)d_out;
  char* ws = (char*)d_ws;

  unsigned* hist  = (unsigned*)(ws + HIST_OFF);
  unsigned* h2    = (unsigned*)(ws + H2_OFF);
  unsigned* ctrl  = (unsigned*)(ws + CTRL_OFF);
  uint4*    keys4 = (uint4*)(ws + KEYS_OFF);
  unsigned* candk = (unsigned*)(ws + CANDK_OFF);
  unsigned* candi = (unsigned*)(ws + CANDI_OFF);
  uint4*    repp  = (uint4*)(ws + REPP_OFF);

  hipMemsetAsync(hist, 0, 2 * NBIN * 4, stream);
  k_keys<<<128, 256, 0, stream>>>((const float4*)q, keys4, hist, ctrl);
  k_compact<<<128, 256, 0, stream>>>(keys4, hist, h2, ctrl, candk, candi);
  k_prep<<<32, 256, 0, stream>>>(q, candk, candi, ctrl, h2, repp);
  k_mfma<<<NQ / 256, 256, 0, stream>>>(q, repp, out);
}